// Round 13
// baseline (47.828 us; speedup 1.0000x reference)
//
#include <hip/hip_runtime.h>
#include <cmath>

#define FDIM 128

typedef __attribute__((ext_vector_type(8))) __bf16 bf16x8;
typedef __attribute__((ext_vector_type(4))) float f32x4;

// RNE f32 -> bf16 bits
__device__ inline unsigned short f2bf(float x) {
  unsigned int u = __float_as_uint(x);
  return (unsigned short)((u + 0x7FFFu + ((u >> 16) & 1u)) >> 16);
}
__device__ inline float bfw_lo(unsigned int w) { return __uint_as_float(w << 16); }
__device__ inline float bfw_hi(unsigned int w) { return __uint_as_float(w & 0xFFFF0000u); }

// phi = silu(h@W1+b1)@W2+b2 (used cols only), two MFMA passes, 16 rows/block,
// 4 waves, weights fragment-packed inline. Output: phiP[s][row][q] u32 packing
// (phi[fb*32+lcol], phi[fb*32+16+lcol]) with q = fb*16+lcol.
__global__ __launch_bounds__(256) void phi_mfma_kernel(
    const float* __restrict__ h, const float* __restrict__ W1, const float* __restrict__ b1,
    const float* __restrict__ W2, const float* __restrict__ b2,
    unsigned int* __restrict__ phiP, int BNA) {
  __shared__ __bf16 hA[4 * 64 * 8];           // 4 KB: h tile (16 rows), A-frag layout
  __shared__ unsigned short tS[16 * 128];     // 4 KB: t tile, swizzled row-major
  const int tid = threadIdx.x;
  const int lane = tid & 63;
  const int w = tid >> 6;       // 0..3
  const int hw = lane >> 4, lcol = lane & 15;
  const int r0 = blockIdx.x * 16;

  // stage h -> A-frag bf16 (one b128 group per thread)
  {
    const int gl = tid & 63;
    const int kt = tid >> 6;
    const int row = gl & 15;
    const int k0 = kt * 32 + ((gl >> 4) << 3);
    const int gr = r0 + row;
    bf16x8 v;
    if (gr < BNA) {
      const float4 f0 = *(const float4*)&h[(size_t)gr * FDIM + k0];
      const float4 f1 = *(const float4*)&h[(size_t)gr * FDIM + k0 + 4];
      v[0] = (__bf16)f0.x; v[1] = (__bf16)f0.y; v[2] = (__bf16)f0.z; v[3] = (__bf16)f0.w;
      v[4] = (__bf16)f1.x; v[5] = (__bf16)f1.y; v[6] = (__bf16)f1.z; v[7] = (__bf16)f1.w;
    } else {
#pragma unroll
      for (int j = 0; j < 8; ++j) v[j] = (__bf16)0.0f;
    }
    *reinterpret_cast<bf16x8*>(&hA[tid * 8]) = v;
  }

  // pass1 B-frags (W1, inline pack): wave w -> f-cols [w*32, w*32+32)
  bf16x8 B1[2][4];
#pragma unroll
  for (int ftl = 0; ftl < 2; ++ftl) {
    const int col = w * 32 + ftl * 16 + lcol;
#pragma unroll
    for (int kt = 0; kt < 4; ++kt)
#pragma unroll
      for (int j = 0; j < 8; ++j)
        B1[ftl][kt][j] = (__bf16)W1[(size_t)(kt * 32 + hw * 8 + j) * FDIM + col];
  }
  float b1v[2];
#pragma unroll
  for (int ftl = 0; ftl < 2; ++ftl) b1v[ftl] = b1[w * 32 + ftl * 16 + lcol];
  __syncthreads();

  {
    bf16x8 ga[4];
#pragma unroll
    for (int kt = 0; kt < 4; ++kt)
      ga[kt] = *reinterpret_cast<const bf16x8*>(&hA[(kt * 64 + lane) * 8]);
    f32x4 acc[2];
    acc[0] = (f32x4){0.f, 0.f, 0.f, 0.f};
    acc[1] = (f32x4){0.f, 0.f, 0.f, 0.f};
#pragma unroll
    for (int ftl = 0; ftl < 2; ++ftl)
#pragma unroll
      for (int kt = 0; kt < 4; ++kt)
        acc[ftl] = __builtin_amdgcn_mfma_f32_16x16x32_bf16(ga[kt], B1[ftl][kt], acc[ftl], 0, 0, 0);
#pragma unroll
    for (int ftl = 0; ftl < 2; ++ftl)
#pragma unroll
      for (int reg = 0; reg < 4; ++reg) {
        const int row = hw * 4 + reg;
        const int fcol = w * 32 + ftl * 16 + lcol;
        const float x = acc[ftl][reg] + b1v[ftl];
        const float t = x / (1.0f + __expf(-x));
        const int byte = (row * 256 + fcol * 2) ^ ((row & 7) << 4);
        *(unsigned short*)((char*)tS + byte) = f2bf(t);
      }
  }

  // pass2 B-frags (W2 used cols, inline pack): wave w -> 64 of 256 f'-cols
  const int s = w >> 1;
  bf16x8 B2[4][4];
#pragma unroll
  for (int ftl = 0; ftl < 4; ++ftl) {
    const int fcol = (w & 1) * 64 + (ftl >> 1) * 32 + (ftl & 1) * 16 + lcol;
    const int col = 3 * fcol + 1 + s;
#pragma unroll
    for (int kt = 0; kt < 4; ++kt)
#pragma unroll
      for (int j = 0; j < 8; ++j)
        B2[ftl][kt][j] = (__bf16)W2[(size_t)(kt * 32 + hw * 8 + j) * 384 + col];
  }
  float b2v[4];
#pragma unroll
  for (int ftl = 0; ftl < 4; ++ftl) {
    const int fcol = (w & 1) * 64 + (ftl >> 1) * 32 + (ftl & 1) * 16 + lcol;
    b2v[ftl] = b2[3 * fcol + 1 + s];
  }
  __syncthreads();

  {
    bf16x8 ta[4];
#pragma unroll
    for (int kt = 0; kt < 4; ++kt) {
      const int row = lcol;
      const int k0 = kt * 32 + hw * 8;
      const int byte = (row * 256 + k0 * 2) ^ ((row & 7) << 4);
      ta[kt] = *reinterpret_cast<const bf16x8*>((const char*)tS + byte);
    }
    f32x4 acc[4];
#pragma unroll
    for (int ftl = 0; ftl < 4; ++ftl) acc[ftl] = (f32x4){0.f, 0.f, 0.f, 0.f};
#pragma unroll
    for (int ftl = 0; ftl < 4; ++ftl)
#pragma unroll
      for (int kt = 0; kt < 4; ++kt)
        acc[ftl] = __builtin_amdgcn_mfma_f32_16x16x32_bf16(ta[kt], B2[ftl][kt], acc[ftl], 0, 0, 0);
#pragma unroll
    for (int p = 0; p < 2; ++p)
#pragma unroll
      for (int reg = 0; reg < 4; ++reg) {
        const int row = hw * 4 + reg;
        const int gr = r0 + row;
        if (gr < BNA) {
          const float vlo = acc[2 * p][reg] + b2v[2 * p];
          const float vhi = acc[2 * p + 1][reg] + b2v[2 * p + 1];
          const unsigned int word = f2bf(vlo) | ((unsigned int)f2bf(vhi) << 16);
          phiP[(size_t)s * BNA * 64 + (size_t)gr * 64 + ((w & 1) * 2 + p) * 16 + lcol] = word;
        }
      }
  }
}

#define DLT  (5.0f / 127.0f)
#define DLT2 (DLT * DLT)
#define E2C  0.99690479f  /* exp(-2*DLT^2) */

// Main fused kernel: 256 threads = 4 waves (1/SIMD), grid (ASPLIT*2, NC, B).
// blockIdx.x encodes (az, s): s = x&1 (0: dH, 1: dV) — split-by-block, so
// every wave keeps only 32 f'-cols (Bf = 32 VGPR) and blocks are uniform.
// Shared G (computed once/block), 128-atom global tiles, unguarded fast path
// for full tiles, cheap pf addressing. __launch_bounds__(256,4): 128-VGPR
// cap -> 4 blocks/CU (LDS 4x34KB=136KB), 16 waves/CU, single dispatch round.
template <int ASPLIT>
__global__ __launch_bounds__(256, 4) void enc_main_kernel(
    const float* __restrict__ xyz, const float* __restrict__ cg_xyz,
    const float* __restrict__ Wf, const float* __restrict__ bf,
    const unsigned int* __restrict__ phiP,
    float* __restrict__ pH, float* __restrict__ pV,
    int NA, int NC, int BNC, int BNA) {
  __shared__ __bf16 Gl[8 * 4 * 64 * 8];  // 32 KB A-frag layout, 128 atoms
  __shared__ float ul[128 * 4];          // 2 KB padded [atom][x,y,z,pad]

  const int az = blockIdx.x >> 1;
  const int s = blockIdx.x & 1;  // 0: dH, 1: dV
  const int c = blockIdx.y;
  const int b = blockIdx.z;
  const int bc = b * NC + c;
  const int tid = threadIdx.x;
  const int lane = tid & 63;
  const int fb = tid >> 6;       // wave = f-block 0..3 (32 cols each)
  const int hw = lane >> 4, lcol = lane & 15;
  const size_t arow = (size_t)b * NA;

  const float cgx = cg_xyz[bc * 3 + 0];
  const float cgy = cg_xyz[bc * 3 + 1];
  const float cgz = cg_xyz[bc * 3 + 2];

  // Global tile split: az owns tiles [t0, t1); only global-last tile ragged.
  const int ntt = (NA + 127) >> 7;
  const int T = (ntt + ASPLIT - 1) / ASPLIT;
  const int t0 = az * T;
  const int t1 = min(ntt, t0 + T);

  // Inline Wf B-frag pack (once): ftl 0..1 -> f'cols fb*32+ftl*16+lcol.
  bf16x8 Bf[2][4];
  float bfv[2];
#pragma unroll
  for (int ftl = 0; ftl < 2; ++ftl) {
    const int col = 3 * (fb * 32 + ftl * 16 + lcol) + 1 + s;
#pragma unroll
    for (int kt = 0; kt < 4; ++kt)
#pragma unroll
      for (int j = 0; j < 8; ++j)
        Bf[ftl][kt][j] = (__bf16)Wf[(size_t)(kt * 32 + hw * 8 + j) * 384 + col];
    bfv[ftl] = bf[3 * (fb * 32 + ftl * 16 + lcol) + 1 + s];
  }

  const unsigned int* __restrict__ phiS = phiP + (size_t)s * BNA * 64;
  const int qoff = fb * 16 + lcol;

  float dHp[2] = {0.f, 0.f};
  float dVp[2][3] = {};

  // G-gen mapping: atom = tid&127, h = tid>>7 covers k in [h*64, h*64+64).
  const int ga_a = tid & 127;
  const int ga_h = tid >> 7;

  for (int t = t0; t < t1; ++t) {
    const int abase = t << 7;
    const bool full = (abase + 128 <= NA);
    __syncthreads();  // prev-tile MFMA/epilogue done reading Gl/ul

    // G generation (shared, once per block): 8 chains of 8 per thread.
    {
      const int a = abase + ga_a;
      float d, ux = 0.f, uy = 0.f, uz = 0.f;
      if (full || a < NA) {
        const float dx = xyz[(arow + a) * 3 + 0] - cgx;
        const float dy = xyz[(arow + a) * 3 + 1] - cgy;
        const float dz = xyz[(arow + a) * 3 + 2] - cgz;
        d = sqrtf(dx * dx + dy * dy + dz * dz);
        const float inv = 1.0f / d;
        ux = dx * inv; uy = dy * inv; uz = dz * inv;
      } else {
        d = 40.0f;  // exp(-(40-o)^2) == 0 for all offsets
      }
      if (ga_h == 0) {
        ul[ga_a * 4 + 0] = ux; ul[ga_a * 4 + 1] = uy; ul[ga_a * 4 + 2] = uz;
      }
      const int sub = ga_a >> 4;
#pragma unroll
      for (int cc = 0; cc < 8; ++cc) {
        const int kb = ga_h * 64 + cc * 8;
        const int kt = kb >> 5;
        const int lg = (kb >> 3) & 3;
        const float d0 = d - (float)kb * DLT;
        float g = __expf(-d0 * d0);
        float r = __expf(2.0f * DLT * d - (float)(2 * kb + 1) * DLT2);
        bf16x8 gv;
#pragma unroll
        for (int j = 0; j < 8; ++j) {
          gv[j] = (__bf16)g;
          g *= r;
          r *= E2C;
        }
        *reinterpret_cast<bf16x8*>(&Gl[((sub * 4 + kt) * 64 + lg * 16 + (ga_a & 15)) * 8]) = gv;
      }
    }
    __syncthreads();

    // MFMA + fused epilogue. phi base pointer per tile (hw folded in);
    // per-sub loads are base[sub*1024 + reg*64] -> cheap addressing.
    const unsigned int* pp = phiS + ((size_t)(arow + abase)) * 64 + qoff + hw * 256;
    unsigned int pfA[4];
    if (full) {
#pragma unroll
      for (int reg = 0; reg < 4; ++reg) pfA[reg] = pp[reg * 64];
    } else {
#pragma unroll
      for (int reg = 0; reg < 4; ++reg) {
        const int a = abase + hw * 4 + reg;
        pfA[reg] = (a < NA) ? pp[reg * 64] : 0u;
      }
    }
#pragma unroll
    for (int sub = 0; sub < 8; ++sub) {
      unsigned int pfB[4];
      if (sub + 1 < 8) {
        const unsigned int* pn = pp + (sub + 1) * 1024;
        if (full) {
#pragma unroll
          for (int reg = 0; reg < 4; ++reg) pfB[reg] = pn[reg * 64];
        } else {
#pragma unroll
          for (int reg = 0; reg < 4; ++reg) {
            const int a = abase + (sub + 1) * 16 + hw * 4 + reg;
            pfB[reg] = (a < NA) ? pn[reg * 64] : 0u;
          }
        }
      }
      bf16x8 ga[4];
#pragma unroll
      for (int kt = 0; kt < 4; ++kt)
        ga[kt] = *reinterpret_cast<const bf16x8*>(&Gl[((sub * 4 + kt) * 64 + lane) * 8]);
      f32x4 acc[2];
      acc[0] = (f32x4){0.f, 0.f, 0.f, 0.f};
      acc[1] = (f32x4){0.f, 0.f, 0.f, 0.f};
      __builtin_amdgcn_s_setprio(1);
#pragma unroll
      for (int ftl = 0; ftl < 2; ++ftl)
#pragma unroll
        for (int kt = 0; kt < 4; ++kt)
          acc[ftl] = __builtin_amdgcn_mfma_f32_16x16x32_bf16(ga[kt], Bf[ftl][kt], acc[ftl], 0, 0, 0);
      __builtin_amdgcn_s_setprio(0);
#pragma unroll
      for (int reg = 0; reg < 4; ++reg) {
        const int a_loc = sub * 16 + hw * 4 + reg;
        const unsigned int pw = pfA[reg];
        const float plo = bfw_lo(pw);
        const float phi_ = bfw_hi(pw);
        if (s == 0) {
          dHp[0] = fmaf(acc[0][reg] + bfv[0], plo, dHp[0]);
          dHp[1] = fmaf(acc[1][reg] + bfv[1], phi_, dHp[1]);
        } else {
          const f32x4 u = *reinterpret_cast<const f32x4*>(&ul[a_loc * 4]);
          const float t0v = (acc[0][reg] + bfv[0]) * plo;
          const float t1v = (acc[1][reg] + bfv[1]) * phi_;
          dVp[0][0] = fmaf(t0v, u[0], dVp[0][0]);
          dVp[0][1] = fmaf(t0v, u[1], dVp[0][1]);
          dVp[0][2] = fmaf(t0v, u[2], dVp[0][2]);
          dVp[1][0] = fmaf(t1v, u[0], dVp[1][0]);
          dVp[1][1] = fmaf(t1v, u[1], dVp[1][1]);
          dVp[1][2] = fmaf(t1v, u[2], dVp[1][2]);
        }
      }
#pragma unroll
      for (int reg = 0; reg < 4; ++reg) pfA[reg] = pfB[reg];
    }
  }

  // reduce across hw groups (lanes sharing lcol) and store partials
#pragma unroll
  for (int ftl = 0; ftl < 2; ++ftl) {
    const int f = fb * 32 + ftl * 16 + lcol;
    if (s == 0) {
      float v = dHp[ftl];
      v += __shfl_xor(v, 16);
      v += __shfl_xor(v, 32);
      if (lane < 16)
        pH[(size_t)(az * BNC + bc) * FDIM + f] = v;
    } else {
#pragma unroll
      for (int x = 0; x < 3; ++x) {
        float v = dVp[ftl][x];
        v += __shfl_xor(v, 16);
        v += __shfl_xor(v, 32);
        if (lane < 16)
          pV[((size_t)(az * BNC + bc) * FDIM + f) * 3 + x] = v;
      }
    }
  }
}

template <int ASPLIT>
__global__ __launch_bounds__(FDIM) void reduce_kernel(
    const float* __restrict__ H, const float* __restrict__ pH, const float* __restrict__ pV,
    float* __restrict__ out, int BNC) {
  const int bc = blockIdx.x;
  const int f = threadIdx.x;
  float s = H[(size_t)bc * FDIM + f];
#pragma unroll
  for (int az = 0; az < ASPLIT; ++az) s += pH[(size_t)(az * BNC + bc) * FDIM + f];
  out[(size_t)bc * FDIM + f] = s;
  float* outV = out + (size_t)BNC * FDIM;
#pragma unroll
  for (int x = 0; x < 3; ++x) {
    float v = 0.f;
#pragma unroll
    for (int az = 0; az < ASPLIT; ++az) v += pV[((size_t)(az * BNC + bc) * FDIM + f) * 3 + x];
    outV[((size_t)bc * FDIM + f) * 3 + x] = v;
  }
}

extern "C" void kernel_launch(void* const* d_in, const int* in_sizes, int n_in,
                              void* d_out, int out_size, void* d_ws, size_t ws_size,
                              hipStream_t stream) {
  // inputs: 0 assign(unused), 1 h, 2 H, 3 cg_xyz, 4 xyz, 5 cg_adj(unused),
  //         6 Wf, 7 bf, 8 W1, 9 b1, 10 W2, 11 b2
  const float* h      = (const float*)d_in[1];
  const float* Hc     = (const float*)d_in[2];
  const float* cg_xyz = (const float*)d_in[3];
  const float* xyz    = (const float*)d_in[4];
  const float* Wf     = (const float*)d_in[6];
  const float* bf     = (const float*)d_in[7];
  const float* W1     = (const float*)d_in[8];
  const float* b1     = (const float*)d_in[9];
  const float* W2     = (const float*)d_in[10];
  const float* b2     = (const float*)d_in[11];

  const int BNC = in_sizes[2] / FDIM;      // B*NC
  const int NC  = in_sizes[5] / BNC;       // cg_adj = B*NC*NC
  const int B   = BNC / NC;
  const int NA  = in_sizes[0] / B;
  const int BNA = B * NA;
  constexpr int ASPLIT = 4;

  // Workspace: phiP (2*BNA*64 u32) + pH + pV
  char* wsb = (char*)d_ws;
  unsigned int* phiP = (unsigned int*)wsb;
  char* p = wsb + (size_t)2 * BNA * 64 * 4;
  float* pH = (float*)p;                   p += (size_t)ASPLIT * BNC * FDIM * 4;
  float* pV = (float*)p;

  phi_mfma_kernel<<<(BNA + 15) / 16, 256, 0, stream>>>(h, W1, b1, W2, b2, phiP, BNA);
  enc_main_kernel<ASPLIT><<<dim3(ASPLIT * 2, NC, B), 256, 0, stream>>>(
      xyz, cg_xyz, Wf, bf, phiP, pH, pV, NA, NC, BNC, BNA);
  reduce_kernel<ASPLIT><<<BNC, FDIM, 0, stream>>>(Hc, pH, pV, (float*)d_out, BNC);
}

// Round 14
// 43.814 us; speedup vs baseline: 1.0916x; 1.0916x over previous
//
#include <hip/hip_runtime.h>
#include <cmath>

#define FDIM 128
#define NPTS 64            /* table points over d in [0, 10.24) */
#define TSTR (NPTS + 1)    /* padded col stride (uint2 units) */
#define TDLT 0.16f
#define INVTDLT 6.25f
#define CLAMPF 62.0f       /* max fidx -> idx<=62, reads idx+1<=63 */

typedef __attribute__((ext_vector_type(8))) __bf16 bf16x8;
typedef __attribute__((ext_vector_type(4))) float f32x4;

// RNE f32 -> bf16 bits
__device__ inline unsigned short f2bf(float x) {
  unsigned int u = __float_as_uint(x);
  return (unsigned short)((u + 0x7FFFu + ((u >> 16) & 1u)) >> 16);
}
__device__ inline float bfw_lo(unsigned int w) { return __uint_as_float(w << 16); }
__device__ inline float bfw_hi(unsigned int w) { return __uint_as_float(w & 0xFFFF0000u); }
__device__ inline float rdlane(float v, int j) {
  return __int_as_float(__builtin_amdgcn_readlane(__float_as_int(v), j));
}

// ---------------------------------------------------------------------------
// Table: Tq[l][pt] (uint2, col stride TSTR) where
//   .x packs bf16(S1(d_pt, f=l)),  bf16(S2(d_pt, f=l))      (lo, hi)
//   .y packs bf16(S1(d_pt, f=l+64)), bf16(S2(d_pt, f=l+64))
// with S_s(d, f) = sum_k exp(-(d - o_k)^2) * Wf[k, 3f+1+s] + bf[3f+1+s].
__global__ __launch_bounds__(128) void build_table_kernel(
    const float* __restrict__ Wf, const float* __restrict__ bf,
    unsigned int* __restrict__ Tq) {
  __shared__ float g[128];
  const int pt = blockIdx.x;
  const int tid = threadIdx.x;  // == f (0..127)
  const float dpt = pt * TDLT;
  const float o = tid * (5.0f / 127.0f);
  const float dd = dpt - o;
  g[tid] = expf(-dd * dd);
  __syncthreads();
  float s0 = bf[3 * tid + 1], s1 = bf[3 * tid + 2];
#pragma unroll 8
  for (int k = 0; k < 128; ++k) {
    s0 = fmaf(g[k], Wf[(size_t)k * 384 + 3 * tid + 1], s0);
    s1 = fmaf(g[k], Wf[(size_t)k * 384 + 3 * tid + 2], s1);
  }
  const unsigned int word = f2bf(s0) | ((unsigned int)f2bf(s1) << 16);
  Tq[((size_t)(tid & 63) * TSTR + pt) * 2 + (tid >> 6)] = word;
}

// ---------------------------------------------------------------------------
// phi = silu(h@W1+b1)@W2+b2 (used cols only), two MFMA passes, 16 rows/block,
// 4 waves, weights fragment-packed inline. Output: phiQ[row][f] u32 packing
// (phi_split1[f] lo, phi_split2[f] hi), f = w*32 + ftl*16 + lcol.
__global__ __launch_bounds__(256) void phi_mfma_kernel(
    const float* __restrict__ h, const float* __restrict__ W1, const float* __restrict__ b1,
    const float* __restrict__ W2, const float* __restrict__ b2,
    unsigned int* __restrict__ phiQ, int BNA) {
  __shared__ __bf16 hA[4 * 64 * 8];           // 4 KB: h tile (16 rows), A-frag layout
  __shared__ unsigned short tS[16 * 128];     // 4 KB: t tile, swizzled row-major
  const int tid = threadIdx.x;
  const int lane = tid & 63;
  const int w = tid >> 6;       // 0..3
  const int hw = lane >> 4, lcol = lane & 15;
  const int r0 = blockIdx.x * 16;

  // stage h -> A-frag bf16 (one b128 group per thread)
  {
    const int gl = tid & 63;
    const int kt = tid >> 6;
    const int row = gl & 15;
    const int k0 = kt * 32 + ((gl >> 4) << 3);
    const int gr = r0 + row;
    bf16x8 v;
    if (gr < BNA) {
      const float4 f0 = *(const float4*)&h[(size_t)gr * FDIM + k0];
      const float4 f1 = *(const float4*)&h[(size_t)gr * FDIM + k0 + 4];
      v[0] = (__bf16)f0.x; v[1] = (__bf16)f0.y; v[2] = (__bf16)f0.z; v[3] = (__bf16)f0.w;
      v[4] = (__bf16)f1.x; v[5] = (__bf16)f1.y; v[6] = (__bf16)f1.z; v[7] = (__bf16)f1.w;
    } else {
#pragma unroll
      for (int j = 0; j < 8; ++j) v[j] = (__bf16)0.0f;
    }
    *reinterpret_cast<bf16x8*>(&hA[tid * 8]) = v;
  }

  // pass1 B-frags (W1, inline pack): wave w -> f-cols [w*32, w*32+32)
  bf16x8 B1[2][4];
#pragma unroll
  for (int ftl = 0; ftl < 2; ++ftl) {
    const int col = w * 32 + ftl * 16 + lcol;
#pragma unroll
    for (int kt = 0; kt < 4; ++kt)
#pragma unroll
      for (int j = 0; j < 8; ++j)
        B1[ftl][kt][j] = (__bf16)W1[(size_t)(kt * 32 + hw * 8 + j) * FDIM + col];
  }
  float b1v[2];
#pragma unroll
  for (int ftl = 0; ftl < 2; ++ftl) b1v[ftl] = b1[w * 32 + ftl * 16 + lcol];
  __syncthreads();

  {
    bf16x8 ga[4];
#pragma unroll
    for (int kt = 0; kt < 4; ++kt)
      ga[kt] = *reinterpret_cast<const bf16x8*>(&hA[(kt * 64 + lane) * 8]);
    f32x4 acc[2];
    acc[0] = (f32x4){0.f, 0.f, 0.f, 0.f};
    acc[1] = (f32x4){0.f, 0.f, 0.f, 0.f};
#pragma unroll
    for (int ftl = 0; ftl < 2; ++ftl)
#pragma unroll
      for (int kt = 0; kt < 4; ++kt)
        acc[ftl] = __builtin_amdgcn_mfma_f32_16x16x32_bf16(ga[kt], B1[ftl][kt], acc[ftl], 0, 0, 0);
#pragma unroll
    for (int ftl = 0; ftl < 2; ++ftl)
#pragma unroll
      for (int reg = 0; reg < 4; ++reg) {
        const int row = hw * 4 + reg;
        const int fcol = w * 32 + ftl * 16 + lcol;
        const float x = acc[ftl][reg] + b1v[ftl];
        const float t = x / (1.0f + __expf(-x));
        const int byte = (row * 256 + fcol * 2) ^ ((row & 7) << 4);
        *(unsigned short*)((char*)tS + byte) = f2bf(t);
      }
  }

  // pass2 B-frags (W2 used cols, BOTH splits, inline pack):
  // wave w -> f-cols [w*32, w*32+32), s in {0,1}.
  bf16x8 B2[2][2][4];  // [ftl][s][kt]
  float b2v[2][2];
#pragma unroll
  for (int ftl = 0; ftl < 2; ++ftl) {
    const int fcol = w * 32 + ftl * 16 + lcol;
#pragma unroll
    for (int s_ = 0; s_ < 2; ++s_) {
      const int col = 3 * fcol + 1 + s_;
#pragma unroll
      for (int kt = 0; kt < 4; ++kt)
#pragma unroll
        for (int j = 0; j < 8; ++j)
          B2[ftl][s_][kt][j] = (__bf16)W2[(size_t)(kt * 32 + hw * 8 + j) * 384 + col];
      b2v[ftl][s_] = b2[col];
    }
  }
  __syncthreads();

  {
    bf16x8 ta[4];
#pragma unroll
    for (int kt = 0; kt < 4; ++kt) {
      const int row = lcol;
      const int k0 = kt * 32 + hw * 8;
      const int byte = (row * 256 + k0 * 2) ^ ((row & 7) << 4);
      ta[kt] = *reinterpret_cast<const bf16x8*>((const char*)tS + byte);
    }
    f32x4 acc[2][2];
#pragma unroll
    for (int ftl = 0; ftl < 2; ++ftl)
#pragma unroll
      for (int s_ = 0; s_ < 2; ++s_) acc[ftl][s_] = (f32x4){0.f, 0.f, 0.f, 0.f};
#pragma unroll
    for (int ftl = 0; ftl < 2; ++ftl)
#pragma unroll
      for (int s_ = 0; s_ < 2; ++s_)
#pragma unroll
        for (int kt = 0; kt < 4; ++kt)
          acc[ftl][s_] = __builtin_amdgcn_mfma_f32_16x16x32_bf16(ta[kt], B2[ftl][s_][kt],
                                                                 acc[ftl][s_], 0, 0, 0);
#pragma unroll
    for (int ftl = 0; ftl < 2; ++ftl)
#pragma unroll
      for (int reg = 0; reg < 4; ++reg) {
        const int row = hw * 4 + reg;
        const int gr = r0 + row;
        if (gr < BNA) {
          const float v0 = acc[ftl][0][reg] + b2v[ftl][0];
          const float v1 = acc[ftl][1][reg] + b2v[ftl][1];
          const unsigned int word = f2bf(v0) | ((unsigned int)f2bf(v1) << 16);
          phiQ[(size_t)gr * FDIM + w * 32 + ftl * 16 + lcol] = word;
        }
      }
  }
}

// ---------------------------------------------------------------------------
// Main kernel (interp): no MFMA, no per-tile barriers. 256 threads = 4 waves,
// grid (ASPLIT, NC, B). Table (33 KB) in LDS -> 4 blocks/CU. Each wave owns a
// private atom chunk and covers ALL 256 outputs: lane l -> f=l and f=l+64,
// both splits. Per atom: readlane-broadcast d/u, 2 LDS uint2 reads, 4 lerps,
// phi from L2 (2-deep prefetch), 10 epilogue fma.
template <int ASPLIT>
__global__ __launch_bounds__(256, 4) void enc_main_kernel(
    const float* __restrict__ xyz, const float* __restrict__ cg_xyz,
    const unsigned int* __restrict__ Tg, const unsigned int* __restrict__ phiQ,
    float* __restrict__ pH, float* __restrict__ pV,
    int NA, int NC, int BNC, int BNA) {
  __shared__ unsigned int Tl[64 * TSTR * 2];  // 33.3 KB

  const int az = blockIdx.x;
  const int c = blockIdx.y;
  const int b = blockIdx.z;
  const int bc = b * NC + c;
  const int tid = threadIdx.x;
  const int l = tid & 63;
  const int wv = tid >> 6;
  const size_t arow = (size_t)b * NA;

  // load table to LDS (uint4 copies)
  {
    const uint4* src4 = (const uint4*)Tg;
    uint4* dst4 = (uint4*)Tl;
#pragma unroll
    for (int i = 0; i < 9; ++i) {
      const int idx = tid + i * 256;
      if (idx < 64 * TSTR * 2 / 4) dst4[idx] = src4[idx];
    }
  }

  const float cgx = cg_xyz[bc * 3 + 0];
  const float cgy = cg_xyz[bc * 3 + 1];
  const float cgz = cg_xyz[bc * 3 + 2];

  // atom chunk for this (az, wave)
  const int APA = (NA + ASPLIT - 1) / ASPLIT;
  const int a0 = az * APA;
  const int a_end = min(NA, a0 + APA);
  const int cnt = (a_end > a0) ? (a_end - a0) : 0;
  const int wcnt = (cnt + 3) >> 2;
  const int aw0 = a0 + wv * wcnt;
  const int aw1 = min(a_end, aw0 + wcnt);

  __syncthreads();  // table ready (only barrier)

  const int lbase = l * TSTR;  // uint2 units

  float accH0 = 0.f, accH1 = 0.f;
  float accV00 = 0.f, accV01 = 0.f, accV02 = 0.f;
  float accV10 = 0.f, accV11 = 0.f, accV12 = 0.f;

  for (int base = aw0; base < aw1; base += 64) {
    int n = aw1 - base;
    if (n > 64) n = 64;

    // batch phase: lane computes its atom's d-index + unit vector
    float fidx = 0.f, ux = 0.f, uy = 0.f, uz = 0.f;
    if (l < n) {
      const int a = base + l;
      const float dx = xyz[(arow + a) * 3 + 0] - cgx;
      const float dy = xyz[(arow + a) * 3 + 1] - cgy;
      const float dz = xyz[(arow + a) * 3 + 2] - cgz;
      const float d = sqrtf(dx * dx + dy * dy + dz * dz);
      const float inv = 1.0f / d;
      ux = dx * inv; uy = dy * inv; uz = dz * inv;
      fidx = fminf(d * INVTDLT, CLAMPF);
    }

    // phi prefetch, 2-deep
    const unsigned int* pq = phiQ + ((size_t)(arow + base)) * FDIM + l;
    unsigned int p0a = 0, p0b = 0, p1a = 0, p1b = 0;
    if (n > 0) { p0a = pq[0];   p0b = pq[64]; }
    if (n > 1) { p1a = pq[128]; p1b = pq[192]; }

    for (int j = 0; j < n; ++j) {
      const float sfidx = rdlane(fidx, j);
      const float sux = rdlane(ux, j);
      const float suy = rdlane(uy, j);
      const float suz = rdlane(uz, j);
      const int idx = (int)sfidx;
      const float frac = sfidx - (float)idx;

      const uint2 t0 = *(const uint2*)&Tl[(lbase + idx) * 2];
      const uint2 t1 = *(const uint2*)&Tl[(lbase + idx + 1) * 2];

      unsigned int pna = 0, pnb = 0;
      if (j + 2 < n) {
        pna = pq[(size_t)(j + 2) * FDIM];
        pnb = pq[(size_t)(j + 2) * FDIM + 64];
      }

      const float A1 = bfw_lo(t0.x), A2 = bfw_hi(t0.x);
      const float B1 = bfw_lo(t1.x), B2 = bfw_hi(t1.x);
      const float C1 = bfw_lo(t0.y), C2 = bfw_hi(t0.y);
      const float D1 = bfw_lo(t1.y), D2 = bfw_hi(t1.y);
      const float S1a = fmaf(frac, B1 - A1, A1);  // split1, f=l   (bias baked in)
      const float S2a = fmaf(frac, B2 - A2, A2);  // split2, f=l
      const float S1b = fmaf(frac, D1 - C1, C1);  // split1, f=l+64
      const float S2b = fmaf(frac, D2 - C2, C2);  // split2, f=l+64

      const float ph1a = bfw_lo(p0a), ph2a = bfw_hi(p0a);
      const float ph1b = bfw_lo(p0b), ph2b = bfw_hi(p0b);

      accH0 = fmaf(S1a, ph1a, accH0);
      accH1 = fmaf(S1b, ph1b, accH1);
      const float t2a = S2a * ph2a;
      const float t2b = S2b * ph2b;
      accV00 = fmaf(t2a, sux, accV00);
      accV01 = fmaf(t2a, suy, accV01);
      accV02 = fmaf(t2a, suz, accV02);
      accV10 = fmaf(t2b, sux, accV10);
      accV11 = fmaf(t2b, suy, accV11);
      accV12 = fmaf(t2b, suz, accV12);

      p0a = p1a; p0b = p1b; p1a = pna; p1b = pnb;
    }
  }

  // write per-(az,wave) partials; lanes own distinct f -> no reduction needed
  const int p = az * 4 + wv;
  float* ph = pH + ((size_t)p * BNC + bc) * FDIM;
  ph[l] = accH0;
  ph[l + 64] = accH1;
  float* pv = pV + ((size_t)p * BNC + bc) * FDIM * 3;
  pv[l * 3 + 0] = accV00; pv[l * 3 + 1] = accV01; pv[l * 3 + 2] = accV02;
  pv[(l + 64) * 3 + 0] = accV10; pv[(l + 64) * 3 + 1] = accV11; pv[(l + 64) * 3 + 2] = accV12;
}

// ---------------------------------------------------------------------------
template <int P>
__global__ __launch_bounds__(FDIM) void reduce_kernel(
    const float* __restrict__ H, const float* __restrict__ pH, const float* __restrict__ pV,
    float* __restrict__ out, int BNC) {
  const int bc = blockIdx.x;
  const int f = threadIdx.x;
  float s = H[(size_t)bc * FDIM + f];
#pragma unroll
  for (int p = 0; p < P; ++p) s += pH[((size_t)p * BNC + bc) * FDIM + f];
  out[(size_t)bc * FDIM + f] = s;
  float* outV = out + (size_t)BNC * FDIM;
#pragma unroll
  for (int x = 0; x < 3; ++x) {
    float v = 0.f;
#pragma unroll
    for (int p = 0; p < P; ++p) v += pV[(((size_t)p * BNC + bc) * FDIM + f) * 3 + x];
    outV[((size_t)bc * FDIM + f) * 3 + x] = v;
  }
}

extern "C" void kernel_launch(void* const* d_in, const int* in_sizes, int n_in,
                              void* d_out, int out_size, void* d_ws, size_t ws_size,
                              hipStream_t stream) {
  // inputs: 0 assign(unused), 1 h, 2 H, 3 cg_xyz, 4 xyz, 5 cg_adj(unused),
  //         6 Wf, 7 bf, 8 W1, 9 b1, 10 W2, 11 b2
  const float* h      = (const float*)d_in[1];
  const float* Hc     = (const float*)d_in[2];
  const float* cg_xyz = (const float*)d_in[3];
  const float* xyz    = (const float*)d_in[4];
  const float* Wf     = (const float*)d_in[6];
  const float* bf     = (const float*)d_in[7];
  const float* W1     = (const float*)d_in[8];
  const float* b1     = (const float*)d_in[9];
  const float* W2     = (const float*)d_in[10];
  const float* b2     = (const float*)d_in[11];

  const int BNC = in_sizes[2] / FDIM;      // B*NC
  const int NC  = in_sizes[5] / BNC;       // cg_adj = B*NC*NC
  const int B   = BNC / NC;
  const int NA  = in_sizes[0] / B;
  const int BNA = B * NA;
  constexpr int ASPLIT = 8;
  constexpr int P = ASPLIT * 4;            // partials per (bc)

  // Workspace: Tq (64*TSTR*2 u32 = 33.3 KB) + phiQ (BNA*128 u32) + pH + pV
  char* wsb = (char*)d_ws;
  unsigned int* Tq   = (unsigned int*)wsb;
  unsigned int* phiQ = (unsigned int*)(wsb + 64 * TSTR * 2 * 4);
  char* pp = wsb + 64 * TSTR * 2 * 4 + (size_t)BNA * FDIM * 4;
  float* pH = (float*)pp;                  pp += (size_t)P * BNC * FDIM * 4;
  float* pV = (float*)pp;

  build_table_kernel<<<NPTS, 128, 0, stream>>>(Wf, bf, Tq);
  phi_mfma_kernel<<<(BNA + 15) / 16, 256, 0, stream>>>(h, W1, b1, W2, b2, phiQ, BNA);
  enc_main_kernel<ASPLIT><<<dim3(ASPLIT, NC, B), 256, 0, stream>>>(
      xyz, cg_xyz, Tq, phiQ, pH, pV, NA, NC, BNC, BNA);
  reduce_kernel<P><<<BNC, FDIM, 0, stream>>>(Hc, pH, pV, (float*)d_out, BNC);
}